// Round 13
// baseline (242.420 us; speedup 1.0000x reference)
//
#include <hip/hip_runtime.h>
#include <math.h>

#define N_NODES 20000
#define N_EDGES 320000
#define EPRIME  (N_EDGES + N_NODES)
#define NP      100000

typedef __bf16 bf16x8 __attribute__((ext_vector_type(8)));
typedef float  f32x4  __attribute__((ext_vector_type(4)));

__device__ __forceinline__ float b2f(unsigned short u) {
    union { float f; unsigned int v; } x; x.v = ((unsigned int)u) << 16; return x.f;
}
__device__ __forceinline__ unsigned short f2b(float f) {
    union { float f; unsigned int v; } x; x.f = f;
    unsigned int r = (x.v + 0x7fffu + ((x.v >> 16) & 1u)) >> 16;
    return (unsigned short)r;
}
__device__ __forceinline__ float lrelu02(float v) { return v > 0.0f ? v : 0.2f * v; }

__device__ __forceinline__ void gload16(const void* g, void* l) {
    __builtin_amdgcn_global_load_lds(
        (const __attribute__((address_space(1))) void*)g,
        (__attribute__((address_space(3))) void*)l, 16, 0, 0);
}

// Bijective XCD chunked swizzle (m204): HW assigns linear block `orig` to
// XCD orig%8. Remap so each XCD owns a CONTIGUOUS chunk of tiles; tiles
// ordered col-major so blocks sharing an A panel are consecutive -> same L2.
__device__ __forceinline__ int xcd_swz(int orig, int n) {
    const int q = n >> 3, r = n & 7;
    const int x = orig & 7, s = orig >> 3;
    return (x < r ? x * (q + 1) : r * (q + 1) + (x - r) * q) + s;
}

// ---------------------------------------------------------------------------
// bf16 MFMA GEMM, BMx128 tile, BK=32, 4 waves (2x2), XOR-swizzled LDS chunks
// (R3, conflict-free). R12 T3/T4 pipeline (3 buffers, counted vmcnt(3), one
// raw s_barrier/step). R13: linear grid + bijective XCD swizzle (A-panel
// sharers co-located per XCD L2).
// EPI: 0 = Cb=bf16(acc); 1 = Cb=bf16(relu(acc+bias));
//      2 = outp[row] += sum_col relu(acc+bias)*w2 (atomic dot, gate)
//      4 = Cb=bf16(acc) + alpha dots -> direct store [row*4+head]
//      5 = Cb=bf16(acc) + alpha dots -> atomicAdd outp/outp2[row]
// ---------------------------------------------------------------------------
template<int BM, int ASRC, int EPI>
__global__ __launch_bounds__(256) void mgemm_k(
    const unsigned short* __restrict__ A0, const unsigned short* __restrict__ A1,
    const unsigned short* __restrict__ BT,
    const float* __restrict__ bias, const float* __restrict__ w2,
    unsigned short* __restrict__ Cb, float* __restrict__ outp,
    float* __restrict__ outp2,
    int M, int K, int Nn, int nwg)
{
    constexpr int NJA   = BM / 64;
    constexpr int MF    = BM / 32;
    constexpr int WROWS = BM / 2;
    static_assert(NJA == 1, "counted vmcnt assumes 3 loads/stage (BM=64)");

    __shared__ unsigned short As[3][BM * 32];
    __shared__ unsigned short Bs[3][4096];

    const int tile = xcd_swz(blockIdx.x, nwg);
    const int bx = tile >> 1, by = tile & 1;     // col-major: A-sharers adjacent

    const int tid = threadIdx.x;
    const int wave = tid >> 6, lane = tid & 63;
    const int row0 = bx * BM, col0 = by * 128;
    const int ksub = (((lane & 3) ^ ((lane >> 3) & 3)) * 8);

    const unsigned short* aL;
    const unsigned short* aH;
    const unsigned short* bP[2];
    {
        const int r = wave * 16 + (lane >> 2);
        int ar = row0 + r; if (ar > M - 1) ar = M - 1;
        if (ASRC == 0) { aL = A0 + (long)ar * K;  aH = aL; }
        else           { aL = A0 + (long)ar * 256; aH = A1 + (long)ar * 256; }
    }
    #pragma unroll
    for (int j = 0; j < 2; ++j) {
        const int r = j * 64 + wave * 16 + (lane >> 2);
        bP[j] = BT + (long)(col0 + r) * K;
    }

    const int wm = wave >> 1, wn = wave & 1;
    const int lrow = lane & 15;
    const int lks = ((((lane >> 4) ^ ((lane >> 1) & 3)) & 3) * 8);

    f32x4 acc[MF][4] = {};

    const int nT = K >> 5;

    auto stage = [&](int bi, int t) {
        const int k0 = t << 5;
        const unsigned short* ga;
        if (ASRC == 0) ga = aL + k0 + ksub;
        else ga = (k0 < 256) ? (aL + k0 + ksub) : (aH + (k0 - 256) + ksub);
        gload16(ga, &As[bi][(wave * 64 + lane) * 8]);
        #pragma unroll
        for (int j = 0; j < 2; ++j)
            gload16(bP[j] + k0 + ksub, &Bs[bi][(j * 256 + wave * 64 + lane) * 8]);
    };

    stage(0, 0);
    stage(1, 1);
    for (int t = 0; t < nT; ++t) {
        if (t >= nT - 1) { asm volatile("s_waitcnt vmcnt(0)" ::: "memory"); }
        else             { asm volatile("s_waitcnt vmcnt(3)" ::: "memory"); }
        __builtin_amdgcn_sched_barrier(0);
        __builtin_amdgcn_s_barrier();
        __builtin_amdgcn_sched_barrier(0);
        if (t + 2 < nT) stage((t + 2) % 3, t + 2);
        const int buf = t % 3;
        bf16x8 a[MF], b[4];
        #pragma unroll
        for (int i = 0; i < MF; ++i)
            a[i] = *(const bf16x8*)&As[buf][(wm * WROWS + i * 16 + lrow) * 32 + lks];
        #pragma unroll
        for (int j = 0; j < 4; ++j)
            b[j] = *(const bf16x8*)&Bs[buf][(wn * 64 + j * 16 + lrow) * 32 + lks];
        asm volatile("s_waitcnt lgkmcnt(0)" ::: "memory");
        __builtin_amdgcn_sched_barrier(0);
        #pragma unroll
        for (int i = 0; i < MF; ++i)
            #pragma unroll
            for (int j = 0; j < 4; ++j)
                acc[i][j] = __builtin_amdgcn_mfma_f32_16x16x32_bf16(a[i], b[j], acc[i][j], 0, 0, 0);
    }

    if constexpr (EPI == 0 || EPI == 1 || EPI == 4 || EPI == 5) {
        #pragma unroll
        for (int i = 0; i < MF; ++i) {
            #pragma unroll
            for (int p = 0; p < 4; ++p) {
                const int row = row0 + wm * WROWS + i * 16 + (lane >> 4) * 4 + p;
                if (row < M) {
                    #pragma unroll
                    for (int j = 0; j < 4; ++j) {
                        const int col = col0 + wn * 64 + j * 16 + (lane & 15);
                        float v = acc[i][j][p];
                        if (EPI == 1) { v += bias[col]; v = v > 0.f ? v : 0.f; }
                        Cb[(long)row * Nn + col] = f2b(v);
                    }
                }
            }
        }
    }
    if constexpr (EPI == 4 || EPI == 5) {
        #pragma unroll
        for (int i = 0; i < MF; ++i) {
            #pragma unroll
            for (int p = 0; p < 4; ++p) {
                float ps = 0.f, pd = 0.f;
                #pragma unroll
                for (int j = 0; j < 4; ++j) {
                    const int col = col0 + wn * 64 + j * 16 + lrow;
                    ps = fmaf(acc[i][j][p], bias[col], ps);
                    pd = fmaf(acc[i][j][p], w2[col], pd);
                }
                #pragma unroll
                for (int off = 1; off < 16; off <<= 1) {
                    ps += __shfl_xor(ps, off);
                    pd += __shfl_xor(pd, off);
                }
                const int row = row0 + wm * WROWS + i * 16 + (lane >> 4) * 4 + p;
                if (lrow == 0 && row < M) {
                    if (EPI == 4) {
                        const int head = (col0 >> 6) + wn;
                        outp[row * 4 + head]  = ps;
                        outp2[row * 4 + head] = pd;
                    } else {
                        atomicAdd(outp + row, ps);
                        atomicAdd(outp2 + row, pd);
                    }
                }
            }
        }
    }
    if constexpr (EPI == 2) {
        float s[MF][4];
        #pragma unroll
        for (int i = 0; i < MF; ++i) {
            #pragma unroll
            for (int p = 0; p < 4; ++p) {
                float t = 0.f;
                #pragma unroll
                for (int j = 0; j < 4; ++j) {
                    const int col = col0 + wn * 64 + j * 16 + (lane & 15);
                    float v = acc[i][j][p] + bias[col];
                    v = v > 0.f ? v : 0.f;
                    t += v * w2[col];
                }
                s[i][p] = t;
            }
        }
        #pragma unroll
        for (int off = 1; off < 16; off <<= 1) {
            #pragma unroll
            for (int i = 0; i < MF; ++i)
                #pragma unroll
                for (int p = 0; p < 4; ++p)
                    s[i][p] += __shfl_xor(s[i][p], off);
        }
        if ((lane & 15) == 0) {
            #pragma unroll
            for (int i = 0; i < MF; ++i)
                #pragma unroll
                for (int p = 0; p < 4; ++p) {
                    const int row = row0 + wm * WROWS + i * 16 + (lane >> 4) * 4 + p;
                    if (row < M) atomicAdd(outp + row, s[i][p]);
                }
        }
    }
}

// ---------------------------------------------------------------------------
// Z-GEMM: 8-wave 128x256, BK=32, T3/T4 pipeline + vectorized LDS epilogue.
// R13: linear 628-block grid + bijective XCD swizzle; by = tile&3 -> the 4
// blocks sharing an A panel are consecutive -> same XCD L2.
// ---------------------------------------------------------------------------
__global__ __launch_bounds__(512) void zgemm_k(
    const unsigned short* __restrict__ A0,   // hf  [N_NODES][256]
    const unsigned short* __restrict__ BT,   // pw1t2 [1024][256]
    const float* __restrict__ bias,          // pb1 (512)
    unsigned short* __restrict__ Cb,         // Z [N_NODES][1024]
    int M)
{
    __shared__ unsigned short lds[36864];    // 72KB: A 3x4096 | B 3x8192

    const int tile = xcd_swz(blockIdx.x, 628);
    const int bx = tile >> 2, by = tile & 3;

    const int tid = threadIdx.x;
    const int wave = tid >> 6, lane = tid & 63;
    const int row0 = bx * 128, col0 = by * 256;
    const int ksub = (((tid & 3) ^ ((tid >> 3) & 3)) * 8);

    const unsigned short* aP;
    {
        int ar = row0 + (tid >> 2); if (ar > M - 1) ar = M - 1;
        aP = A0 + (long)ar * 256;
    }
    const unsigned short* bP[2];
    #pragma unroll
    for (int j = 0; j < 2; ++j)
        bP[j] = BT + (long)(col0 + j * 128 + (tid >> 2)) * 256;

    const int wm = wave >> 2, wn = wave & 3;
    const int lrow = lane & 15, g = lane >> 4;
    const int lks = ((((lane >> 4) ^ ((lane >> 1) & 3)) & 3) * 8);

    f32x4 acc[4][4] = {};

    auto stage = [&](int bi, int t) {
        const int k0 = t << 5;
        gload16(aP + k0 + ksub, &lds[bi * 4096 + tid * 8]);
        #pragma unroll
        for (int j = 0; j < 2; ++j)
            gload16(bP[j] + k0 + ksub, &lds[12288 + bi * 8192 + (j * 512 + tid) * 8]);
    };

    stage(0, 0);
    stage(1, 1);
    #pragma unroll
    for (int t = 0; t < 8; ++t) {
        if (t >= 7) { asm volatile("s_waitcnt vmcnt(0)" ::: "memory"); }
        else        { asm volatile("s_waitcnt vmcnt(3)" ::: "memory"); }
        __builtin_amdgcn_sched_barrier(0);
        __builtin_amdgcn_s_barrier();
        __builtin_amdgcn_sched_barrier(0);
        if (t + 2 < 8) stage((t + 2) % 3, t + 2);
        const unsigned short* as_b = &lds[(t % 3) * 4096];
        const unsigned short* bs_b = &lds[12288 + (t % 3) * 8192];
        bf16x8 a[4], b[4];
        #pragma unroll
        for (int i = 0; i < 4; ++i)
            a[i] = *(const bf16x8*)&as_b[(wm * 64 + i * 16 + lrow) * 32 + lks];
        #pragma unroll
        for (int j = 0; j < 4; ++j)
            b[j] = *(const bf16x8*)&bs_b[(wn * 64 + j * 16 + lrow) * 32 + lks];
        asm volatile("s_waitcnt lgkmcnt(0)" ::: "memory");
        __builtin_amdgcn_sched_barrier(0);
        #pragma unroll
        for (int i = 0; i < 4; ++i)
            #pragma unroll
            for (int j = 0; j < 4; ++j)
                acc[i][j] = __builtin_amdgcn_mfma_f32_16x16x32_bf16(a[i], b[j], acc[i][j], 0, 0, 0);
    }
    __syncthreads();

    unsigned short* Cs = lds;
    #pragma unroll
    for (int h = 0; h < 2; ++h) {
        if (wm == h) {
            #pragma unroll
            for (int i = 0; i < 4; ++i)
                #pragma unroll
                for (int j = 0; j < 4; ++j)
                    #pragma unroll
                    for (int p = 0; p < 4; ++p) {
                        const int r = i * 16 + g * 4 + p;
                        const int c = wn * 64 + j * 16 + lrow;
                        float v = acc[i][j][p];
                        const int col = col0 + c;
                        if (col < 512) v += bias[col];
                        Cs[r * 256 + c] = f2b(v);
                    }
        }
        __syncthreads();
        #pragma unroll
        for (int q = 0; q < 4; ++q) {
            const int cq = q * 512 + tid;
            const int r = cq >> 5, ch = cq & 31;
            const int row = row0 + h * 64 + r;
            if (row < M)
                *(ulonglong2*)&Cb[(long)row * 1024 + col0 + ch * 8] =
                    *(const ulonglong2*)&Cs[r * 256 + ch * 8];
        }
        __syncthreads();
    }
}

// ---------------------------------------------------------------------------
// pair combine: out[p] = relu(Zt[u] + Zb[v]) . pw2 + pb2
// ---------------------------------------------------------------------------
__global__ __launch_bounds__(256) void pair_k(
    const unsigned short* __restrict__ Z, const int* __restrict__ un,
    const int* __restrict__ vn, const float* __restrict__ pw2,
    const float* __restrict__ pb2, float* __restrict__ out)
{
    const int wv = threadIdx.x >> 6, lane = threadIdx.x & 63;
    const int p = blockIdx.x * 4 + wv;
    if (p >= NP) return;
    const int u = un[p], v = vn[p];
    const int c0 = lane * 8;
    const uint4 zu = *(const uint4*)&Z[(long)u * 1024 + c0];
    const uint4 zv = *(const uint4*)&Z[(long)v * 1024 + 512 + c0];
    const float4 w2a = *(const float4*)&pw2[c0];
    const float4 w2b = *(const float4*)&pw2[c0 + 4];

    float zt[8], zb[8];
    zt[0] = b2f(zu.x & 0xffff); zt[1] = b2f(zu.x >> 16);
    zt[2] = b2f(zu.y & 0xffff); zt[3] = b2f(zu.y >> 16);
    zt[4] = b2f(zu.z & 0xffff); zt[5] = b2f(zu.z >> 16);
    zt[6] = b2f(zu.w & 0xffff); zt[7] = b2f(zu.w >> 16);
    zb[0] = b2f(zv.x & 0xffff); zb[1] = b2f(zv.x >> 16);
    zb[2] = b2f(zv.y & 0xffff); zb[3] = b2f(zv.y >> 16);
    zb[4] = b2f(zv.z & 0xffff); zb[5] = b2f(zv.z >> 16);
    zb[6] = b2f(zv.w & 0xffff); zb[7] = b2f(zv.w >> 16);

    const float ww[8] = {w2a.x, w2a.y, w2a.z, w2a.w, w2b.x, w2b.y, w2b.z, w2b.w};
    float s = 0.f;
    #pragma unroll
    for (int q = 0; q < 8; ++q) {
        float t = zt[q] + zb[q];
        t = t > 0.f ? t : 0.f;
        s = fmaf(t, ww[q], s);
    }
    #pragma unroll
    for (int off = 1; off < 64; off <<= 1) s += __shfl_xor(s, off);
    if (lane == 0) out[p] = s + pb2[0];
}

// ---------------------------------------------------------------------------
// fused prep: x cast + 4 weight transposes + deg init + zero(gacc,as2,ad2)
// ---------------------------------------------------------------------------
__global__ __launch_bounds__(256) void prep_k(
    const float* __restrict__ x, unsigned short* __restrict__ xb,
    const float* __restrict__ W1, unsigned short* __restrict__ W1t,
    const float* __restrict__ W2, unsigned short* __restrict__ W2t,
    const float* __restrict__ gw1, unsigned short* __restrict__ gw1t,
    const float* __restrict__ pw1, unsigned short* __restrict__ pw1t2,
    int* __restrict__ deg, float* __restrict__ gacc,
    float* __restrict__ as2v, float* __restrict__ ad2v)
{
    const int bid = blockIdx.x, tid = threadIdx.x;
    if (bid < 5000) {
        const int id = bid * 256 + tid;
        const float4 v = ((const float4*)x)[id];
        ushort4 o;
        o.x = f2b(v.x); o.y = f2b(v.y); o.z = f2b(v.z); o.w = f2b(v.w);
        ((ushort4*)xb)[id] = o;
    } else if (bid < 5256) {
        const int id = (bid - 5000) * 256 + tid;
        W1t[(id & 255) * 256 + (id >> 8)] = f2b(W1[id]);
    } else if (bid < 5512) {
        const int id = (bid - 5256) * 256 + tid;
        W2t[(id & 255) * 256 + (id >> 8)] = f2b(W2[id]);
    } else if (bid < 6024) {
        const int id = (bid - 5512) * 256 + tid;
        gw1t[(id & 255) * 512 + (id >> 8)] = f2b(gw1[id]);
    } else if (bid < 7048) {
        const int id = (bid - 6024) * 256 + tid;
        const int r = id >> 9, c = id & 511;
        const int j = (r < 256) ? c : (512 + c);
        const int k = (r < 256) ? r : (r - 256);
        pw1t2[j * 256 + k] = f2b(pw1[id]);
    } else if (bid < 7127) {
        const int i = (bid - 7048) * 256 + tid;
        if (i < N_NODES) deg[i] = 1;
    } else {
        const int i = (bid - 7127) * 256 + tid;
        if (i < 20000) gacc[i] = 0.f;
        else if (i < 40000) as2v[i - 20000] = 0.f;
        else if (i < 60000) ad2v[i - 40000] = 0.f;
    }
}

// ---------------------------------------------------------------------------
// CSR construction
// ---------------------------------------------------------------------------
__global__ __launch_bounds__(256) void deg_count_k(const int* __restrict__ ei, int* __restrict__ deg)
{
    const int e = blockIdx.x * 256 + threadIdx.x;
    if (e < N_EDGES) atomicAdd(&deg[ei[N_EDGES + e]], 1);
}

__global__ __launch_bounds__(1024) void scan_k(const int* __restrict__ deg,
                                               int* __restrict__ indptr,
                                               int* __restrict__ pos)
{
    __shared__ int sums[1024];
    const int tid = threadIdx.x;
    const int CH = 20;
    const int start = tid * CH;
    const int end = min(start + CH, N_NODES);
    int s = 0;
    for (int i = start; i < end; ++i) s += deg[i];
    sums[tid] = s;
    __syncthreads();
    for (int off = 1; off < 1024; off <<= 1) {
        const int v = sums[tid];
        const int add = (tid >= off) ? sums[tid - off] : 0;
        __syncthreads();
        sums[tid] = v + add;
        __syncthreads();
    }
    int pre = sums[tid] - s;
    for (int i = start; i < end; ++i) {
        indptr[i] = pre;
        pos[i] = pre;
        pre += deg[i];
    }
    if (tid == 1023) indptr[N_NODES] = sums[1023];
}

__global__ __launch_bounds__(256) void fill_k(const int* __restrict__ ei,
                                              int* __restrict__ pos, int* __restrict__ csr)
{
    const int i = blockIdx.x * 256 + threadIdx.x;
    if (i < N_EDGES) {
        const int s = ei[i], d = ei[N_EDGES + i];
        const int p = atomicAdd(&pos[d], 1);
        csr[p] = s;
    } else if (i < EPRIME) {
        const int n = i - N_EDGES;
        const int p = atomicAdd(&pos[n], 1);
        csr[p] = n;
    }
}

// ---------------------------------------------------------------------------
// Fused GAT aggregation conv1: one wave per node, single pass.
// ---------------------------------------------------------------------------
__global__ __launch_bounds__(256) void agg1_k(
    const unsigned short* __restrict__ h1, const float* __restrict__ as1,
    const float* __restrict__ ad1, const int* __restrict__ indptr,
    const int* __restrict__ csr, const float* __restrict__ b1,
    unsigned short* __restrict__ out)
{
    __shared__ int   ssrc[4][64];
    __shared__ float sp[4][64 * 4];
    const int wv = threadIdx.x >> 6, lane = threadIdx.x & 63;
    const int n = blockIdx.x * 4 + wv;
    if (n >= N_NODES) return;

    const int beg = indptr[n], end = indptr[n + 1];
    const float4 ad = ((const float4*)ad1)[n];
    const int c0 = lane * 4;
    const int hd = lane >> 4;

    float acc[4] = {0.f, 0.f, 0.f, 0.f};
    float psum[4] = {0.f, 0.f, 0.f, 0.f};

    for (int base = beg; base < end; base += 64) {
        const int cnt = min(64, end - base);
        if (lane < cnt) {
            const int s = csr[base + lane];
            const float4 av = ((const float4*)as1)[s];
            float4 p;
            p.x = __expf(lrelu02(av.x + ad.x));
            p.y = __expf(lrelu02(av.y + ad.y));
            p.z = __expf(lrelu02(av.z + ad.z));
            p.w = __expf(lrelu02(av.w + ad.w));
            ssrc[wv][lane] = s;
            *(float4*)&sp[wv][lane * 4] = p;
            psum[0] += p.x; psum[1] += p.y; psum[2] += p.z; psum[3] += p.w;
        }
        asm volatile("s_waitcnt lgkmcnt(0)" ::: "memory");
        __builtin_amdgcn_sched_barrier(0);
        for (int e = 0; e < cnt; ++e) {
            const int s = ssrc[wv][e];
            const float w = sp[wv][e * 4 + hd];
            const ushort4 hv = *(const ushort4*)&h1[(long)s * 256 + c0];
            acc[0] = fmaf(w, b2f(hv.x), acc[0]);
            acc[1] = fmaf(w, b2f(hv.y), acc[1]);
            acc[2] = fmaf(w, b2f(hv.z), acc[2]);
            acc[3] = fmaf(w, b2f(hv.w), acc[3]);
        }
        __builtin_amdgcn_sched_barrier(0);
        __builtin_amdgcn_wave_barrier();
    }

    #pragma unroll
    for (int off = 1; off < 64; off <<= 1) {
        #pragma unroll
        for (int h = 0; h < 4; ++h) psum[h] += __shfl_xor(psum[h], off);
    }
    const float invd = 1.0f / psum[hd];

    ushort4 o;
    float v;
    v = acc[0] * invd + b1[c0 + 0]; o.x = f2b(v > 0.f ? v : (__expf(v) - 1.0f));
    v = acc[1] * invd + b1[c0 + 1]; o.y = f2b(v > 0.f ? v : (__expf(v) - 1.0f));
    v = acc[2] * invd + b1[c0 + 2]; o.z = f2b(v > 0.f ? v : (__expf(v) - 1.0f));
    v = acc[3] * invd + b1[c0 + 3]; o.w = f2b(v > 0.f ? v : (__expf(v) - 1.0f));
    *(ushort4*)&out[(long)n * 256 + c0] = o;
}

// conv2: 1 head x 256 ch, +b2
__global__ __launch_bounds__(256) void agg2_k(
    const unsigned short* __restrict__ h2, const float* __restrict__ as2,
    const float* __restrict__ ad2, const int* __restrict__ indptr,
    const int* __restrict__ csr, const float* __restrict__ b2,
    unsigned short* __restrict__ outb)
{
    __shared__ int   ssrc[4][64];
    __shared__ float sp[4][64];
    const int wv = threadIdx.x >> 6, lane = threadIdx.x & 63;
    const int n = blockIdx.x * 4 + wv;
    if (n >= N_NODES) return;

    const int beg = indptr[n], end = indptr[n + 1];
    const float adv = ad2[n];
    const int c0 = lane * 4;

    float acc[4] = {0.f, 0.f, 0.f, 0.f};
    float psum = 0.f;

    for (int base = beg; base < end; base += 64) {
        const int cnt = min(64, end - base);
        if (lane < cnt) {
            const int s = csr[base + lane];
            const float p = __expf(lrelu02(as2[s] + adv));
            ssrc[wv][lane] = s;
            sp[wv][lane] = p;
            psum += p;
        }
        asm volatile("s_waitcnt lgkmcnt(0)" ::: "memory");
        __builtin_amdgcn_sched_barrier(0);
        for (int e = 0; e < cnt; ++e) {
            const int s = ssrc[wv][e];
            const float w = sp[wv][e];
            const ushort4 hv = *(const ushort4*)&h2[(long)s * 256 + c0];
            acc[0] = fmaf(w, b2f(hv.x), acc[0]);
            acc[1] = fmaf(w, b2f(hv.y), acc[1]);
            acc[2] = fmaf(w, b2f(hv.z), acc[2]);
            acc[3] = fmaf(w, b2f(hv.w), acc[3]);
        }
        __builtin_amdgcn_sched_barrier(0);
        __builtin_amdgcn_wave_barrier();
    }

    #pragma unroll
    for (int off = 1; off < 64; off <<= 1) psum += __shfl_xor(psum, off);
    const float invd = 1.0f / psum;

    ushort4 o;
    o.x = f2b(acc[0] * invd + b2[c0 + 0]);
    o.y = f2b(acc[1] * invd + b2[c0 + 1]);
    o.z = f2b(acc[2] * invd + b2[c0 + 2]);
    o.w = f2b(acc[3] * invd + b2[c0 + 3]);
    *(ushort4*)&outb[(long)n * 256 + c0] = o;
}

// ---------------------------------------------------------------------------
// gate finalize from pre-reduced dot: g = sigmoid(gacc[n]+gb2); blend -> hfb
// ---------------------------------------------------------------------------
__global__ __launch_bounds__(256) void gatefin2_k(
    const float* __restrict__ gacc, const float* __restrict__ gb2,
    const float* __restrict__ x, const unsigned short* __restrict__ hgb,
    unsigned short* __restrict__ hfb)
{
    const int wid = threadIdx.x >> 6;
    const int lane = threadIdx.x & 63;
    const int n = blockIdx.x * 4 + wid;
    if (n >= N_NODES) return;
    const float g = 1.0f / (1.0f + __expf(-(gacc[n] + gb2[0])));
    #pragma unroll
    for (int q = 0; q < 4; ++q) {
        const int c = q * 64 + lane;
        const float xv = x[(long)n * 256 + c];
        const float hv = b2f(hgb[(long)n * 256 + c]);
        hfb[(long)n * 256 + c] = f2b((1.0f - g) * xv + g * hv);
    }
}

// ---------------------------------------------------------------------------
extern "C" void kernel_launch(void* const* d_in, const int* in_sizes, int n_in,
                              void* d_out, int out_size, void* d_ws, size_t ws_size,
                              hipStream_t stream)
{
    const float* x   = (const float*)d_in[0];
    const int*   ei  = (const int*)d_in[1];
    const int*   un  = (const int*)d_in[2];
    const int*   vn  = (const int*)d_in[3];
    const float* W1  = (const float*)d_in[4];
    const float* a1s = (const float*)d_in[5];
    const float* a1d = (const float*)d_in[6];
    const float* b1  = (const float*)d_in[7];
    const float* W2  = (const float*)d_in[8];
    const float* a2s = (const float*)d_in[9];
    const float* a2d = (const float*)d_in[10];
    const float* b2  = (const float*)d_in[11];
    const float* gw1 = (const float*)d_in[12];
    const float* gb1 = (const float*)d_in[13];
    const float* gw2 = (const float*)d_in[14];
    const float* gb2 = (const float*)d_in[15];
    const float* pw1 = (const float*)d_in[16];
    const float* pb1 = (const float*)d_in[17];
    const float* pw2 = (const float*)d_in[18];
    const float* pb2 = (const float*)d_in[19];
    float* out = (float*)d_out;

    dim3 b256(256);

    if (ws_size < 58720256u) return;

    unsigned short* Z     = (unsigned short*)d_ws;
    unsigned short* bufHb = Z;
    unsigned short* hgb   = Z + 5120000;
    unsigned short* xb    = Z + 10240000;
    unsigned short* hfb   = Z + 20480000;
    unsigned short* W1t   = hfb + 5120000;
    unsigned short* W2t   = W1t + 65536;
    unsigned short* gw1t  = W2t + 65536;
    unsigned short* pw1t2 = gw1t + 131072;           // [1024][256]
    float* as1v = (float*)(pw1t2 + 262144);
    float* ad1v = as1v + 80000;
    float* as2v = ad1v + 80000;
    float* ad2v = as2v + 20000;
    int* deg    = (int*)(ad2v + 20000);
    int* indptr = deg + 20000;
    int* pos    = indptr + 20032;
    int* csr    = pos + 20000;
    float* gacc = (float*)(csr + EPRIME);

    prep_k<<<7362, b256, 0, stream>>>(x, xb, W1, W1t, W2, W2t, gw1, gw1t,
                                      pw1, pw1t2, deg, gacc, as2v, ad2v);
    deg_count_k<<<(N_EDGES + 255) / 256, b256, 0, stream>>>(ei, deg);
    scan_k<<<1, 1024, 0, stream>>>(deg, indptr, pos);
    fill_k<<<(EPRIME + 255) / 256, b256, 0, stream>>>(ei, pos, csr);

    // conv1 (+fused alpha1: direct head-wise stores)
    mgemm_k<64, 0, 4><<<626, b256, 0, stream>>>(
        xb, nullptr, W1t, a1s, a1d, bufHb, as1v, ad1v, N_NODES, 256, 256, 626);
    agg1_k<<<5000, b256, 0, stream>>>(bufHb, as1v, ad1v, indptr, csr, b1, hfb);

    // conv2 (+fused alpha2: atomic partial dots)
    mgemm_k<64, 0, 5><<<626, b256, 0, stream>>>(
        hfb, nullptr, W2t, a2s, a2d, bufHb, as2v, ad2v, N_NODES, 256, 256, 626);
    agg2_k<<<5000, b256, 0, stream>>>(bufHb, as2v, ad2v, indptr, csr, b2, hgb);

    // gate: atomic dot epilogue, no ghid materialization
    mgemm_k<64, 1, 2><<<626, b256, 0, stream>>>(
        xb, hgb, gw1t, gb1, gw2, nullptr, gacc, nullptr, N_NODES, 512, 256, 626);
    gatefin2_k<<<5000, b256, 0, stream>>>(gacc, gb2, x, hgb, hfb);

    // Z = hf @ [pw1_top | pw1_bot] (+pb1 on cols<512) — XCD-swizzled grid
    zgemm_k<<<628, dim3(512), 0, stream>>>(hfb, pw1t2, pb1, Z, N_NODES);

    pair_k<<<25000, b256, 0, stream>>>(Z, un, vn, pw2, pb2, out);
}

// Round 15
// 230.921 us; speedup vs baseline: 1.0498x; 1.0498x over previous
//
#include <hip/hip_runtime.h>
#include <math.h>

#define N_NODES 20000
#define N_EDGES 320000
#define EPRIME  (N_EDGES + N_NODES)
#define NP      100000

typedef __bf16 bf16x8 __attribute__((ext_vector_type(8)));
typedef float  f32x4  __attribute__((ext_vector_type(4)));

__device__ __forceinline__ float b2f(unsigned short u) {
    union { float f; unsigned int v; } x; x.v = ((unsigned int)u) << 16; return x.f;
}
__device__ __forceinline__ unsigned short f2b(float f) {
    union { float f; unsigned int v; } x; x.f = f;
    unsigned int r = (x.v + 0x7fffu + ((x.v >> 16) & 1u)) >> 16;
    return (unsigned short)r;
}
__device__ __forceinline__ float lrelu02(float v) { return v > 0.0f ? v : 0.2f * v; }

__device__ __forceinline__ void gload16(const void* g, void* l) {
    __builtin_amdgcn_global_load_lds(
        (const __attribute__((address_space(1))) void*)g,
        (__attribute__((address_space(3))) void*)l, 16, 0, 0);
}

// ---------------------------------------------------------------------------
// bf16 MFMA GEMM, BMx128 tile, BK=32, 4 waves (2x2), XOR-swizzled LDS chunks
// (R3, conflict-free, counter-verified). T3/T4 pipeline (R12 proven): 3 LDS
// buffers, 2-deep prefetch, counted vmcnt(3), ONE raw s_barrier per K-step.
// EPI: 0 = Cb=bf16(acc); 1 = Cb=bf16(relu(acc+bias));
//      2 = outp[row] += sum_col relu(acc+bias)*w2 (atomic dot, gate)
//      4 = Cb=bf16(acc) + alpha dots -> direct store [row*4+head]
//      5 = Cb=bf16(acc) + alpha dots -> atomicAdd outp/outp2[row]
// ---------------------------------------------------------------------------
template<int BM, int ASRC, int EPI>
__global__ __launch_bounds__(256) void mgemm_k(
    const unsigned short* __restrict__ A0, const unsigned short* __restrict__ A1,
    const unsigned short* __restrict__ BT,
    const float* __restrict__ bias, const float* __restrict__ w2,
    unsigned short* __restrict__ Cb, float* __restrict__ outp,
    float* __restrict__ outp2,
    int M, int K, int Nn)
{
    constexpr int NJA   = BM / 64;
    constexpr int MF    = BM / 32;
    constexpr int WROWS = BM / 2;
    static_assert(NJA == 1, "counted vmcnt assumes 3 loads/stage (BM=64)");

    __shared__ unsigned short As[3][BM * 32];
    __shared__ unsigned short Bs[3][4096];

    const int tid = threadIdx.x;
    const int wave = tid >> 6, lane = tid & 63;
    const int row0 = blockIdx.x * BM, col0 = blockIdx.y * 128;
    const int ksub = (((lane & 3) ^ ((lane >> 3) & 3)) * 8);

    const unsigned short* aL;
    const unsigned short* aH;
    const unsigned short* bP[2];
    {
        const int r = wave * 16 + (lane >> 2);
        int ar = row0 + r; if (ar > M - 1) ar = M - 1;
        if (ASRC == 0) { aL = A0 + (long)ar * K;  aH = aL; }
        else           { aL = A0 + (long)ar * 256; aH = A1 + (long)ar * 256; }
    }
    #pragma unroll
    for (int j = 0; j < 2; ++j) {
        const int r = j * 64 + wave * 16 + (lane >> 2);
        bP[j] = BT + (long)(col0 + r) * K;
    }

    const int wm = wave >> 1, wn = wave & 1;
    const int lrow = lane & 15;
    const int lks = ((((lane >> 4) ^ ((lane >> 1) & 3)) & 3) * 8);

    f32x4 acc[MF][4] = {};

    const int nT = K >> 5;

    auto stage = [&](int bi, int t) {
        const int k0 = t << 5;
        const unsigned short* ga;
        if (ASRC == 0) ga = aL + k0 + ksub;
        else ga = (k0 < 256) ? (aL + k0 + ksub) : (aH + (k0 - 256) + ksub);
        gload16(ga, &As[bi][(wave * 64 + lane) * 8]);
        #pragma unroll
        for (int j = 0; j < 2; ++j)
            gload16(bP[j] + k0 + ksub, &Bs[bi][(j * 256 + wave * 64 + lane) * 8]);
    };

    stage(0, 0);
    stage(1, 1);
    for (int t = 0; t < nT; ++t) {
        if (t >= nT - 1) { asm volatile("s_waitcnt vmcnt(0)" ::: "memory"); }
        else             { asm volatile("s_waitcnt vmcnt(3)" ::: "memory"); }
        __builtin_amdgcn_sched_barrier(0);
        __builtin_amdgcn_s_barrier();
        __builtin_amdgcn_sched_barrier(0);
        if (t + 2 < nT) stage((t + 2) % 3, t + 2);
        const int buf = t % 3;
        bf16x8 a[MF], b[4];
        #pragma unroll
        for (int i = 0; i < MF; ++i)
            a[i] = *(const bf16x8*)&As[buf][(wm * WROWS + i * 16 + lrow) * 32 + lks];
        #pragma unroll
        for (int j = 0; j < 4; ++j)
            b[j] = *(const bf16x8*)&Bs[buf][(wn * 64 + j * 16 + lrow) * 32 + lks];
        asm volatile("s_waitcnt lgkmcnt(0)" ::: "memory");
        __builtin_amdgcn_sched_barrier(0);
        #pragma unroll
        for (int i = 0; i < MF; ++i)
            #pragma unroll
            for (int j = 0; j < 4; ++j)
                acc[i][j] = __builtin_amdgcn_mfma_f32_16x16x32_bf16(a[i], b[j], acc[i][j], 0, 0, 0);
    }

    if constexpr (EPI == 0 || EPI == 1 || EPI == 4 || EPI == 5) {
        #pragma unroll
        for (int i = 0; i < MF; ++i) {
            #pragma unroll
            for (int p = 0; p < 4; ++p) {
                const int row = row0 + wm * WROWS + i * 16 + (lane >> 4) * 4 + p;
                if (row < M) {
                    #pragma unroll
                    for (int j = 0; j < 4; ++j) {
                        const int col = col0 + wn * 64 + j * 16 + (lane & 15);
                        float v = acc[i][j][p];
                        if (EPI == 1) { v += bias[col]; v = v > 0.f ? v : 0.f; }
                        Cb[(long)row * Nn + col] = f2b(v);
                    }
                }
            }
        }
    }
    if constexpr (EPI == 4 || EPI == 5) {
        #pragma unroll
        for (int i = 0; i < MF; ++i) {
            #pragma unroll
            for (int p = 0; p < 4; ++p) {
                float ps = 0.f, pd = 0.f;
                #pragma unroll
                for (int j = 0; j < 4; ++j) {
                    const int col = col0 + wn * 64 + j * 16 + lrow;
                    ps = fmaf(acc[i][j][p], bias[col], ps);
                    pd = fmaf(acc[i][j][p], w2[col], pd);
                }
                #pragma unroll
                for (int off = 1; off < 16; off <<= 1) {
                    ps += __shfl_xor(ps, off);
                    pd += __shfl_xor(pd, off);
                }
                const int row = row0 + wm * WROWS + i * 16 + (lane >> 4) * 4 + p;
                if (lrow == 0 && row < M) {
                    if (EPI == 4) {
                        const int head = (col0 >> 6) + wn;
                        outp[row * 4 + head]  = ps;
                        outp2[row * 4 + head] = pd;
                    } else {
                        atomicAdd(outp + row, ps);
                        atomicAdd(outp2 + row, pd);
                    }
                }
            }
        }
    }
    if constexpr (EPI == 2) {
        float s[MF][4];
        #pragma unroll
        for (int i = 0; i < MF; ++i) {
            #pragma unroll
            for (int p = 0; p < 4; ++p) {
                float t = 0.f;
                #pragma unroll
                for (int j = 0; j < 4; ++j) {
                    const int col = col0 + wn * 64 + j * 16 + (lane & 15);
                    float v = acc[i][j][p] + bias[col];
                    v = v > 0.f ? v : 0.f;
                    t += v * w2[col];
                }
                s[i][p] = t;
            }
        }
        #pragma unroll
        for (int off = 1; off < 16; off <<= 1) {
            #pragma unroll
            for (int i = 0; i < MF; ++i)
                #pragma unroll
                for (int p = 0; p < 4; ++p)
                    s[i][p] += __shfl_xor(s[i][p], off);
        }
        if ((lane & 15) == 0) {
            #pragma unroll
            for (int i = 0; i < MF; ++i)
                #pragma unroll
                for (int p = 0; p < 4; ++p) {
                    const int row = row0 + wm * WROWS + i * 16 + (lane >> 4) * 4 + p;
                    if (row < M) atomicAdd(outp + row, s[i][p]);
                }
        }
    }
}

// ---------------------------------------------------------------------------
// Z-GEMM: 8-wave 128x256, BK=32, T3/T4 pipeline + vectorized LDS epilogue
// (R12 proven form, 236.45us total).
// ---------------------------------------------------------------------------
__global__ __launch_bounds__(512) void zgemm_k(
    const unsigned short* __restrict__ A0,
    const unsigned short* __restrict__ BT,
    const float* __restrict__ bias,
    unsigned short* __restrict__ Cb,
    int M)
{
    __shared__ unsigned short lds[36864];

    const int tid = threadIdx.x;
    const int wave = tid >> 6, lane = tid & 63;
    const int row0 = blockIdx.x * 128, col0 = blockIdx.y * 256;
    const int ksub = (((tid & 3) ^ ((tid >> 3) & 3)) * 8);

    const unsigned short* aP;
    {
        int ar = row0 + (tid >> 2); if (ar > M - 1) ar = M - 1;
        aP = A0 + (long)ar * 256;
    }
    const unsigned short* bP[2];
    #pragma unroll
    for (int j = 0; j < 2; ++j)
        bP[j] = BT + (long)(col0 + j * 128 + (tid >> 2)) * 256;

    const int wm = wave >> 2, wn = wave & 3;
    const int lrow = lane & 15, g = lane >> 4;
    const int lks = ((((lane >> 4) ^ ((lane >> 1) & 3)) & 3) * 8);

    f32x4 acc[4][4] = {};

    auto stage = [&](int bi, int t) {
        const int k0 = t << 5;
        gload16(aP + k0 + ksub, &lds[bi * 4096 + tid * 8]);
        #pragma unroll
        for (int j = 0; j < 2; ++j)
            gload16(bP[j] + k0 + ksub, &lds[12288 + bi * 8192 + (j * 512 + tid) * 8]);
    };

    stage(0, 0);
    stage(1, 1);
    #pragma unroll
    for (int t = 0; t < 8; ++t) {
        if (t >= 7) { asm volatile("s_waitcnt vmcnt(0)" ::: "memory"); }
        else        { asm volatile("s_waitcnt vmcnt(3)" ::: "memory"); }
        __builtin_amdgcn_sched_barrier(0);
        __builtin_amdgcn_s_barrier();
        __builtin_amdgcn_sched_barrier(0);
        if (t + 2 < 8) stage((t + 2) % 3, t + 2);
        const unsigned short* as_b = &lds[(t % 3) * 4096];
        const unsigned short* bs_b = &lds[12288 + (t % 3) * 8192];
        bf16x8 a[4], b[4];
        #pragma unroll
        for (int i = 0; i < 4; ++i)
            a[i] = *(const bf16x8*)&as_b[(wm * 64 + i * 16 + lrow) * 32 + lks];
        #pragma unroll
        for (int j = 0; j < 4; ++j)
            b[j] = *(const bf16x8*)&bs_b[(wn * 64 + j * 16 + lrow) * 32 + lks];
        asm volatile("s_waitcnt lgkmcnt(0)" ::: "memory");
        __builtin_amdgcn_sched_barrier(0);
        #pragma unroll
        for (int i = 0; i < 4; ++i)
            #pragma unroll
            for (int j = 0; j < 4; ++j)
                acc[i][j] = __builtin_amdgcn_mfma_f32_16x16x32_bf16(a[i], b[j], acc[i][j], 0, 0, 0);
    }
    __syncthreads();

    unsigned short* Cs = lds;
    #pragma unroll
    for (int h = 0; h < 2; ++h) {
        if (wm == h) {
            #pragma unroll
            for (int i = 0; i < 4; ++i)
                #pragma unroll
                for (int j = 0; j < 4; ++j)
                    #pragma unroll
                    for (int p = 0; p < 4; ++p) {
                        const int r = i * 16 + g * 4 + p;
                        const int c = wn * 64 + j * 16 + lrow;
                        float v = acc[i][j][p];
                        const int col = col0 + c;
                        if (col < 512) v += bias[col];
                        Cs[r * 256 + c] = f2b(v);
                    }
        }
        __syncthreads();
        #pragma unroll
        for (int q = 0; q < 4; ++q) {
            const int cq = q * 512 + tid;
            const int r = cq >> 5, ch = cq & 31;
            const int row = row0 + h * 64 + r;
            if (row < M)
                *(ulonglong2*)&Cb[(long)row * 1024 + col0 + ch * 8] =
                    *(const ulonglong2*)&Cs[r * 256 + ch * 8];
        }
        __syncthreads();
    }
}

// ---------------------------------------------------------------------------
// pair combine: out[p] = relu(Zt[u] + Zb[v]) . pw2 + pb2
// ---------------------------------------------------------------------------
__global__ __launch_bounds__(256) void pair_k(
    const unsigned short* __restrict__ Z, const int* __restrict__ un,
    const int* __restrict__ vn, const float* __restrict__ pw2,
    const float* __restrict__ pb2, float* __restrict__ out)
{
    const int wv = threadIdx.x >> 6, lane = threadIdx.x & 63;
    const int p = blockIdx.x * 4 + wv;
    if (p >= NP) return;
    const int u = un[p], v = vn[p];
    const int c0 = lane * 8;
    const uint4 zu = *(const uint4*)&Z[(long)u * 1024 + c0];
    const uint4 zv = *(const uint4*)&Z[(long)v * 1024 + 512 + c0];
    const float4 w2a = *(const float4*)&pw2[c0];
    const float4 w2b = *(const float4*)&pw2[c0 + 4];

    float zt[8], zb[8];
    zt[0] = b2f(zu.x & 0xffff); zt[1] = b2f(zu.x >> 16);
    zt[2] = b2f(zu.y & 0xffff); zt[3] = b2f(zu.y >> 16);
    zt[4] = b2f(zu.z & 0xffff); zt[5] = b2f(zu.z >> 16);
    zt[6] = b2f(zu.w & 0xffff); zt[7] = b2f(zu.w >> 16);
    zb[0] = b2f(zv.x & 0xffff); zb[1] = b2f(zv.x >> 16);
    zb[2] = b2f(zv.y & 0xffff); zb[3] = b2f(zv.y >> 16);
    zb[4] = b2f(zv.z & 0xffff); zb[5] = b2f(zv.z >> 16);
    zb[6] = b2f(zv.w & 0xffff); zb[7] = b2f(zv.w >> 16);

    const float ww[8] = {w2a.x, w2a.y, w2a.z, w2a.w, w2b.x, w2b.y, w2b.z, w2b.w};
    float s = 0.f;
    #pragma unroll
    for (int q = 0; q < 8; ++q) {
        float t = zt[q] + zb[q];
        t = t > 0.f ? t : 0.f;
        s = fmaf(t, ww[q], s);
    }
    #pragma unroll
    for (int off = 1; off < 64; off <<= 1) s += __shfl_xor(s, off);
    if (lane == 0) out[p] = s + pb2[0];
}

// ---------------------------------------------------------------------------
// fused prep: x cast + 4 weight transposes + deg init + zero(gacc,as2,ad2)
// (R12 proven form — deg COUNTING stays a separate kernel; fusing the atomics
// here raced the deg=1 init and corrupted the CSR in R13.)
// ---------------------------------------------------------------------------
__global__ __launch_bounds__(256) void prep_k(
    const float* __restrict__ x, unsigned short* __restrict__ xb,
    const float* __restrict__ W1, unsigned short* __restrict__ W1t,
    const float* __restrict__ W2, unsigned short* __restrict__ W2t,
    const float* __restrict__ gw1, unsigned short* __restrict__ gw1t,
    const float* __restrict__ pw1, unsigned short* __restrict__ pw1t2,
    int* __restrict__ deg, float* __restrict__ gacc,
    float* __restrict__ as2v, float* __restrict__ ad2v)
{
    const int bid = blockIdx.x, tid = threadIdx.x;
    if (bid < 5000) {
        const int id = bid * 256 + tid;
        const float4 v = ((const float4*)x)[id];
        ushort4 o;
        o.x = f2b(v.x); o.y = f2b(v.y); o.z = f2b(v.z); o.w = f2b(v.w);
        ((ushort4*)xb)[id] = o;
    } else if (bid < 5256) {
        const int id = (bid - 5000) * 256 + tid;
        W1t[(id & 255) * 256 + (id >> 8)] = f2b(W1[id]);
    } else if (bid < 5512) {
        const int id = (bid - 5256) * 256 + tid;
        W2t[(id & 255) * 256 + (id >> 8)] = f2b(W2[id]);
    } else if (bid < 6024) {
        const int id = (bid - 5512) * 256 + tid;
        gw1t[(id & 255) * 512 + (id >> 8)] = f2b(gw1[id]);
    } else if (bid < 7048) {
        const int id = (bid - 6024) * 256 + tid;
        const int r = id >> 9, c = id & 511;
        const int j = (r < 256) ? c : (512 + c);
        const int k = (r < 256) ? r : (r - 256);
        pw1t2[j * 256 + k] = f2b(pw1[id]);
    } else if (bid < 7127) {
        const int i = (bid - 7048) * 256 + tid;
        if (i < N_NODES) deg[i] = 1;   // self-loop
    } else {
        const int i = (bid - 7127) * 256 + tid;
        if (i < 20000) gacc[i] = 0.f;
        else if (i < 40000) as2v[i - 20000] = 0.f;
        else if (i < 60000) ad2v[i - 40000] = 0.f;
    }
}

// ---------------------------------------------------------------------------
// CSR construction (R12 proven)
// ---------------------------------------------------------------------------
__global__ __launch_bounds__(256) void deg_count_k(const int* __restrict__ ei, int* __restrict__ deg)
{
    const int e = blockIdx.x * 256 + threadIdx.x;
    if (e < N_EDGES) atomicAdd(&deg[ei[N_EDGES + e]], 1);
}

__global__ __launch_bounds__(1024) void scan_k(const int* __restrict__ deg,
                                               int* __restrict__ indptr,
                                               int* __restrict__ pos)
{
    __shared__ int sums[1024];
    const int tid = threadIdx.x;
    const int CH = 20;
    const int start = tid * CH;
    const int end = min(start + CH, N_NODES);
    int s = 0;
    for (int i = start; i < end; ++i) s += deg[i];
    sums[tid] = s;
    __syncthreads();
    for (int off = 1; off < 1024; off <<= 1) {
        const int v = sums[tid];
        const int add = (tid >= off) ? sums[tid - off] : 0;
        __syncthreads();
        sums[tid] = v + add;
        __syncthreads();
    }
    int pre = sums[tid] - s;
    for (int i = start; i < end; ++i) {
        indptr[i] = pre;
        pos[i] = pre;
        pre += deg[i];
    }
    if (tid == 1023) indptr[N_NODES] = sums[1023];
}

__global__ __launch_bounds__(256) void fill_k(const int* __restrict__ ei,
                                              int* __restrict__ pos, int* __restrict__ csr)
{
    const int i = blockIdx.x * 256 + threadIdx.x;
    if (i < N_EDGES) {
        const int s = ei[i], d = ei[N_EDGES + i];
        const int p = atomicAdd(&pos[d], 1);
        csr[p] = s;
    } else if (i < EPRIME) {
        const int n = i - N_EDGES;
        const int p = atomicAdd(&pos[n], 1);
        csr[p] = n;
    }
}

// ---------------------------------------------------------------------------
// Fused GAT aggregation conv1: one wave per node, gather unrolled x4
// (4 independent 8B loads in flight per lane; bounded by cnt, race-free).
// ---------------------------------------------------------------------------
__global__ __launch_bounds__(256) void agg1_k(
    const unsigned short* __restrict__ h1, const float* __restrict__ as1,
    const float* __restrict__ ad1, const int* __restrict__ indptr,
    const int* __restrict__ csr, const float* __restrict__ b1,
    unsigned short* __restrict__ out)
{
    __shared__ int   ssrc[4][64];
    __shared__ float sp[4][64 * 4];
    const int wv = threadIdx.x >> 6, lane = threadIdx.x & 63;
    const int n = blockIdx.x * 4 + wv;
    if (n >= N_NODES) return;

    const int beg = indptr[n], end = indptr[n + 1];
    const float4 ad = ((const float4*)ad1)[n];
    const int c0 = lane * 4;
    const int hd = lane >> 4;

    float acc[4] = {0.f, 0.f, 0.f, 0.f};
    float psum[4] = {0.f, 0.f, 0.f, 0.f};

    for (int base = beg; base < end; base += 64) {
        const int cnt = min(64, end - base);
        if (lane < cnt) {
            const int s = csr[base + lane];
            const float4 av = ((const float4*)as1)[s];
            float4 p;
            p.x = __expf(lrelu02(av.x + ad.x));
            p.y = __expf(lrelu02(av.y + ad.y));
            p.z = __expf(lrelu02(av.z + ad.z));
            p.w = __expf(lrelu02(av.w + ad.w));
            ssrc[wv][lane] = s;
            *(float4*)&sp[wv][lane * 4] = p;
            psum[0] += p.x; psum[1] += p.y; psum[2] += p.z; psum[3] += p.w;
        }
        asm volatile("s_waitcnt lgkmcnt(0)" ::: "memory");
        __builtin_amdgcn_sched_barrier(0);
        int e = 0;
        for (; e + 4 <= cnt; e += 4) {
            const int s0 = ssrc[wv][e], s1 = ssrc[wv][e + 1];
            const int s2 = ssrc[wv][e + 2], s3 = ssrc[wv][e + 3];
            const float w0 = sp[wv][(e + 0) * 4 + hd], w1 = sp[wv][(e + 1) * 4 + hd];
            const float w2v = sp[wv][(e + 2) * 4 + hd], w3 = sp[wv][(e + 3) * 4 + hd];
            const ushort4 h0 = *(const ushort4*)&h1[(long)s0 * 256 + c0];
            const ushort4 h1v = *(const ushort4*)&h1[(long)s1 * 256 + c0];
            const ushort4 h2v = *(const ushort4*)&h1[(long)s2 * 256 + c0];
            const ushort4 h3v = *(const ushort4*)&h1[(long)s3 * 256 + c0];
            acc[0] = fmaf(w0, b2f(h0.x), acc[0]);  acc[1] = fmaf(w0, b2f(h0.y), acc[1]);
            acc[2] = fmaf(w0, b2f(h0.z), acc[2]);  acc[3] = fmaf(w0, b2f(h0.w), acc[3]);
            acc[0] = fmaf(w1, b2f(h1v.x), acc[0]); acc[1] = fmaf(w1, b2f(h1v.y), acc[1]);
            acc[2] = fmaf(w1, b2f(h1v.z), acc[2]); acc[3] = fmaf(w1, b2f(h1v.w), acc[3]);
            acc[0] = fmaf(w2v, b2f(h2v.x), acc[0]); acc[1] = fmaf(w2v, b2f(h2v.y), acc[1]);
            acc[2] = fmaf(w2v, b2f(h2v.z), acc[2]); acc[3] = fmaf(w2v, b2f(h2v.w), acc[3]);
            acc[0] = fmaf(w3, b2f(h3v.x), acc[0]); acc[1] = fmaf(w3, b2f(h3v.y), acc[1]);
            acc[2] = fmaf(w3, b2f(h3v.z), acc[2]); acc[3] = fmaf(w3, b2f(h3v.w), acc[3]);
        }
        for (; e < cnt; ++e) {
            const int s = ssrc[wv][e];
            const float w = sp[wv][e * 4 + hd];
            const ushort4 hv = *(const ushort4*)&h1[(long)s * 256 + c0];
            acc[0] = fmaf(w, b2f(hv.x), acc[0]);
            acc[1] = fmaf(w, b2f(hv.y), acc[1]);
            acc[2] = fmaf(w, b2f(hv.z), acc[2]);
            acc[3] = fmaf(w, b2f(hv.w), acc[3]);
        }
        __builtin_amdgcn_sched_barrier(0);
        __builtin_amdgcn_wave_barrier();
    }

    #pragma unroll
    for (int off = 1; off < 64; off <<= 1) {
        #pragma unroll
        for (int h = 0; h < 4; ++h) psum[h] += __shfl_xor(psum[h], off);
    }
    const float invd = 1.0f / psum[hd];

    ushort4 o;
    float v;
    v = acc[0] * invd + b1[c0 + 0]; o.x = f2b(v > 0.f ? v : (__expf(v) - 1.0f));
    v = acc[1] * invd + b1[c0 + 1]; o.y = f2b(v > 0.f ? v : (__expf(v) - 1.0f));
    v = acc[2] * invd + b1[c0 + 2]; o.z = f2b(v > 0.f ? v : (__expf(v) - 1.0f));
    v = acc[3] * invd + b1[c0 + 3]; o.w = f2b(v > 0.f ? v : (__expf(v) - 1.0f));
    *(ushort4*)&out[(long)n * 256 + c0] = o;
}

// conv2: 1 head x 256 ch, +b2, gather unrolled x4
__global__ __launch_bounds__(256) void agg2_k(
    const unsigned short* __restrict__ h2, const float* __restrict__ as2,
    const float* __restrict__ ad2, const int* __restrict__ indptr,
    const int* __restrict__ csr, const float* __restrict__ b2,
    unsigned short* __restrict__ outb)
{
    __shared__ int   ssrc[4][64];
    __shared__ float sp[4][64];
    const int wv = threadIdx.x >> 6, lane = threadIdx.x & 63;
    const int n = blockIdx.x * 4 + wv;
    if (n >= N_NODES) return;

    const int beg = indptr[n], end = indptr[n + 1];
    const float adv = ad2[n];
    const int c0 = lane * 4;

    float acc[4] = {0.f, 0.f, 0.f, 0.f};
    float psum = 0.f;

    for (int base = beg; base < end; base += 64) {
        const int cnt = min(64, end - base);
        if (lane < cnt) {
            const int s = csr[base + lane];
            const float p = __expf(lrelu02(as2[s] + adv));
            ssrc[wv][lane] = s;
            sp[wv][lane] = p;
            psum += p;
        }
        asm volatile("s_waitcnt lgkmcnt(0)" ::: "memory");
        __builtin_amdgcn_sched_barrier(0);
        int e = 0;
        for (; e + 4 <= cnt; e += 4) {
            const int s0 = ssrc[wv][e], s1 = ssrc[wv][e + 1];
            const int s2 = ssrc[wv][e + 2], s3 = ssrc[wv][e + 3];
            const float w0 = sp[wv][e], w1 = sp[wv][e + 1];
            const float w2v = sp[wv][e + 2], w3 = sp[wv][e + 3];
            const ushort4 h0 = *(const ushort4*)&h2[(long)s0 * 256 + c0];
            const ushort4 h1v = *(const ushort4*)&h2[(long)s1 * 256 + c0];
            const ushort4 h2u = *(const ushort4*)&h2[(long)s2 * 256 + c0];
            const ushort4 h3v = *(const ushort4*)&h2[(long)s3 * 256 + c0];
            acc[0] = fmaf(w0, b2f(h0.x), acc[0]);  acc[1] = fmaf(w0, b2f(h0.y), acc[1]);
            acc[2] = fmaf(w0, b2f(h0.z), acc[2]);  acc[3] = fmaf(w0, b2f(h0.w), acc[3]);
            acc[0] = fmaf(w1, b2f(h1v.x), acc[0]); acc[1] = fmaf(w1, b2f(h1v.y), acc[1]);
            acc[2] = fmaf(w1, b2f(h1v.z), acc[2]); acc[3] = fmaf(w1, b2f(h1v.w), acc[3]);
            acc[0] = fmaf(w2v, b2f(h2u.x), acc[0]); acc[1] = fmaf(w2v, b2f(h2u.y), acc[1]);
            acc[2] = fmaf(w2v, b2f(h2u.z), acc[2]); acc[3] = fmaf(w2v, b2f(h2u.w), acc[3]);
            acc[0] = fmaf(w3, b2f(h3v.x), acc[0]); acc[1] = fmaf(w3, b2f(h3v.y), acc[1]);
            acc[2] = fmaf(w3, b2f(h3v.z), acc[2]); acc[3] = fmaf(w3, b2f(h3v.w), acc[3]);
        }
        for (; e < cnt; ++e) {
            const int s = ssrc[wv][e];
            const float w = sp[wv][e];
            const ushort4 hv = *(const ushort4*)&h2[(long)s * 256 + c0];
            acc[0] = fmaf(w, b2f(hv.x), acc[0]);
            acc[1] = fmaf(w, b2f(hv.y), acc[1]);
            acc[2] = fmaf(w, b2f(hv.z), acc[2]);
            acc[3] = fmaf(w, b2f(hv.w), acc[3]);
        }
        __builtin_amdgcn_sched_barrier(0);
        __builtin_amdgcn_wave_barrier();
    }

    #pragma unroll
    for (int off = 1; off < 64; off <<= 1) psum += __shfl_xor(psum, off);
    const float invd = 1.0f / psum;

    ushort4 o;
    o.x = f2b(acc[0] * invd + b2[c0 + 0]);
    o.y = f2b(acc[1] * invd + b2[c0 + 1]);
    o.z = f2b(acc[2] * invd + b2[c0 + 2]);
    o.w = f2b(acc[3] * invd + b2[c0 + 3]);
    *(ushort4*)&outb[(long)n * 256 + c0] = o;
}

// ---------------------------------------------------------------------------
// gate finalize from pre-reduced dot
// ---------------------------------------------------------------------------
__global__ __launch_bounds__(256) void gatefin2_k(
    const float* __restrict__ gacc, const float* __restrict__ gb2,
    const float* __restrict__ x, const unsigned short* __restrict__ hgb,
    unsigned short* __restrict__ hfb)
{
    const int wid = threadIdx.x >> 6;
    const int lane = threadIdx.x & 63;
    const int n = blockIdx.x * 4 + wid;
    if (n >= N_NODES) return;
    const float g = 1.0f / (1.0f + __expf(-(gacc[n] + gb2[0])));
    #pragma unroll
    for (int q = 0; q < 4; ++q) {
        const int c = q * 64 + lane;
        const float xv = x[(long)n * 256 + c];
        const float hv = b2f(hgb[(long)n * 256 + c]);
        hfb[(long)n * 256 + c] = f2b((1.0f - g) * xv + g * hv);
    }
}

// ---------------------------------------------------------------------------
extern "C" void kernel_launch(void* const* d_in, const int* in_sizes, int n_in,
                              void* d_out, int out_size, void* d_ws, size_t ws_size,
                              hipStream_t stream)
{
    const float* x   = (const float*)d_in[0];
    const int*   ei  = (const int*)d_in[1];
    const int*   un  = (const int*)d_in[2];
    const int*   vn  = (const int*)d_in[3];
    const float* W1  = (const float*)d_in[4];
    const float* a1s = (const float*)d_in[5];
    const float* a1d = (const float*)d_in[6];
    const float* b1  = (const float*)d_in[7];
    const float* W2  = (const float*)d_in[8];
    const float* a2s = (const float*)d_in[9];
    const float* a2d = (const float*)d_in[10];
    const float* b2  = (const float*)d_in[11];
    const float* gw1 = (const float*)d_in[12];
    const float* gb1 = (const float*)d_in[13];
    const float* gw2 = (const float*)d_in[14];
    const float* gb2 = (const float*)d_in[15];
    const float* pw1 = (const float*)d_in[16];
    const float* pb1 = (const float*)d_in[17];
    const float* pw2 = (const float*)d_in[18];
    const float* pb2 = (const float*)d_in[19];
    float* out = (float*)d_out;

    dim3 b256(256);

    if (ws_size < 58720256u) return;

    unsigned short* Z     = (unsigned short*)d_ws;
    unsigned short* bufHb = Z;
    unsigned short* hgb   = Z + 5120000;
    unsigned short* xb    = Z + 10240000;
    unsigned short* hfb   = Z + 20480000;
    unsigned short* W1t   = hfb + 5120000;
    unsigned short* W2t   = W1t + 65536;
    unsigned short* gw1t  = W2t + 65536;
    unsigned short* pw1t2 = gw1t + 131072;
    float* as1v = (float*)(pw1t2 + 262144);
    float* ad1v = as1v + 80000;
    float* as2v = ad1v + 80000;
    float* ad2v = as2v + 20000;
    int* deg    = (int*)(ad2v + 20000);
    int* indptr = deg + 20000;
    int* pos    = indptr + 20032;
    int* csr    = pos + 20000;
    float* gacc = (float*)(csr + EPRIME);

    prep_k<<<7362, b256, 0, stream>>>(x, xb, W1, W1t, W2, W2t, gw1, gw1t,
                                      pw1, pw1t2, deg, gacc, as2v, ad2v);
    deg_count_k<<<(N_EDGES + 255) / 256, b256, 0, stream>>>(ei, deg);
    scan_k<<<1, 1024, 0, stream>>>(deg, indptr, pos);
    fill_k<<<(EPRIME + 255) / 256, b256, 0, stream>>>(ei, pos, csr);

    // conv1 (+fused alpha1: direct head-wise stores)
    mgemm_k<64, 0, 4><<<dim3(313, 2), b256, 0, stream>>>(
        xb, nullptr, W1t, a1s, a1d, bufHb, as1v, ad1v, N_NODES, 256, 256);
    agg1_k<<<5000, b256, 0, stream>>>(bufHb, as1v, ad1v, indptr, csr, b1, hfb);

    // conv2 (+fused alpha2: atomic partial dots)
    mgemm_k<64, 0, 5><<<dim3(313, 2), b256, 0, stream>>>(
        hfb, nullptr, W2t, a2s, a2d, bufHb, as2v, ad2v, N_NODES, 256, 256);
    agg2_k<<<5000, b256, 0, stream>>>(bufHb, as2v, ad2v, indptr, csr, b2, hgb);

    // gate: atomic dot epilogue, no ghid materialization
    mgemm_k<64, 1, 2><<<dim3(313, 2), b256, 0, stream>>>(
        xb, hgb, gw1t, gb1, gw2, nullptr, gacc, nullptr, N_NODES, 512, 256);
    gatefin2_k<<<5000, b256, 0, stream>>>(gacc, gb2, x, hgb, hfb);

    // Z = hf @ [pw1_top | pw1_bot] (+pb1 on cols<512)
    zgemm_k<<<dim3(157, 4), dim3(512), 0, stream>>>(hfb, pw1t2, pb1, Z, N_NODES);

    pair_k<<<25000, b256, 0, stream>>>(Z, un, vn, pw2, pb2, out);
}